// Round 2
// baseline (4603.008 us; speedup 1.0000x reference)
//
#include <hip/hip_runtime.h>

#define B_TOT    1024
#define TM1      127
#define NE       128
#define STRIDE   132          // floats; 132*4=528 B rows (16B-aligned), bank spread 4g+c
#define NTHREADS 512
#define NBLOCKS  256
#define ROUNDS   (B_TOT / NBLOCKS)

__device__ __forceinline__ float fast_tanh(float x) {
    float e = __expf(2.0f * x);                       // inf -> tanh=1 (correct)
    return 1.0f - 2.0f * __builtin_amdgcn_rcpf(e + 1.0f);
}
__device__ __forceinline__ float fast_sig(float x) {
    return __builtin_amdgcn_rcpf(1.0f + __expf(-x));
}

__global__ __attribute__((amdgpu_flat_work_group_size(NTHREADS, NTHREADS),
                          amdgpu_waves_per_eu(2, 2)))   // LDS caps us at 2 waves/EU anyway -> 256 VGPR budget
void decoder_kernel(const float* __restrict__ Xg,     // (B,127,128)
                    const float* __restrict__ yprev,  // (B,127)
                    const float* __restrict__ W1,     // (384,128): [d;c;x] rows
                    const float* __restrict__ b1,
                    const float* __restrict__ W2,     // (128)
                    const float* __restrict__ b2v,
                    const float* __restrict__ Wfc,    // (129)
                    const float* __restrict__ bfcv,
                    const float* __restrict__ Wx,     // (512)
                    const float* __restrict__ Wh,     // (128,512)
                    const float* __restrict__ blv,    // (512)
                    const float* __restrict__ Wf,     // (256)
                    const float* __restrict__ bfv,
                    float* __restrict__ out)          // (B)
{
    __shared__ __align__(16) float Xs  [128 * STRIDE];
    __shared__ __align__(16) float preX[128 * STRIDE];
    __shared__ __align__(16) float sdc [256];   // d(0..127), c(128..255)
    __shared__ __align__(16) float u_s [128];
    __shared__ __align__(16) float w2s [128];
    __shared__ float betas[128];
    __shared__ float XWfcs[128];
    __shared__ float ys   [TM1];
    __shared__ float swave[8];
    __shared__ float scrE [128];

    const int tid = threadIdx.x;
    const int e   = tid & 127;      // staging / preX mapping
    const int hq  = tid >> 7;
    const int g   = tid >> 2;       // group 0..127: t' (B), e (A), gate-slot (E)
    const int q   = tid & 3;        // quarter; reduction partners = adjacent lanes
    const int wv  = tid >> 6;

    const float4* sdc4 = (const float4*)sdc;
    const float4* u4p  = (const float4*)u_s;
    const float4* w24p = (const float4*)w2s;

    // ---- persistent register weights (q-rotated to match LDS read order) ----
    float w1r[64];                                   // W1dc[k][g], k split by quarter
    #pragma unroll
    for (int i4 = 0; i4 < 16; ++i4) {
        const int j = q * 16 + ((i4 + q * 4) & 15);  // float4 idx into sdc (0..63)
        #pragma unroll
        for (int m = 0; m < 4; ++m)
            w1r[i4 * 4 + m] = W1[(j * 4 + m) * NE + g];
    }
    float whr[128];                                  // [gate*32 + i]: Wh[k][gate*128+g]
    #pragma unroll
    for (int i4 = 0; i4 < 8; ++i4) {
        const int j = q * 8 + ((i4 + q * 2) & 7);    // float4 idx into d (0..31)
        #pragma unroll
        for (int m = 0; m < 4; ++m) {
            const int k = j * 4 + m;
            #pragma unroll
            for (int gate = 0; gate < 4; ++gate)
                whr[gate * 32 + i4 * 4 + m] = Wh[k * 512 + gate * 128 + g];
        }
    }

    const float b1r   = b1[e];
    const float b2q   = b2v[0] * 0.25f;              // added per-quarter, sums to b2
    const float bfc_r = bfcv[0];
    const float wfcy  = Wfc[NE];
    const float wx0 = Wx[g], wx1 = Wx[128 + g], wx2 = Wx[256 + g], wx3 = Wx[384 + g];
    const float bl0 = blv[g], bl1 = blv[128 + g], bl2 = blv[256 + g], bl3 = blv[384 + g];
    const float bf_r = bfv[0];

    if (tid < 128) w2s[tid] = W2[tid];               // constant across rounds

    for (int r = 0; r < ROUNDS; ++r) {
        const int b = (int)blockIdx.x + r * NBLOCKS;
        const float* __restrict__ Xb = Xg + (size_t)b * (TM1 * NE);

        if (tid < 128) {
            float x00 = Xb[0];                        // d0 = c0 = X[b,0,0]
            sdc[tid]       = x00;
            sdc[128 + tid] = x00;
        }
        if (tid < TM1) ys[tid] = yprev[(size_t)b * TM1 + tid];
        #pragma unroll
        for (int i = 0; i < 32; ++i) {                // coalesced X stage, row 127 = 0
            int tp = hq * 32 + i;
            Xs[tp * STRIDE + e] = (tp < TM1) ? Xb[tp * NE + e] : 0.0f;
        }
        __syncthreads();

        // ---- preX[t'][e] = b1 + X[t']@W1_x ----
        #pragma unroll
        for (int gg = 0; gg < 4; ++gg) {
            float acc[8];
            #pragma unroll
            for (int j = 0; j < 8; ++j) acc[j] = b1r;
            for (int k = 0; k < 128; ++k) {
                float w = W1[(256 + k) * NE + e];     // coalesced, L2-hot
                #pragma unroll
                for (int j = 0; j < 8; ++j)
                    acc[j] = fmaf(w, Xs[(hq * 32 + gg * 8 + j) * STRIDE + k], acc[j]);
            }
            #pragma unroll
            for (int j = 0; j < 8; ++j)
                preX[(hq * 32 + gg * 8 + j) * STRIDE + e] = acc[j];
        }
        // ---- XWfc[t'] = X[t'] . Wfc  (ctx eliminated per-step via this) ----
        {
            float p = 0.0f;
            #pragma unroll
            for (int i = 0; i < 32; ++i) {
                int ee = q * 32 + ((i + q * 8) & 31);
                p = fmaf(Xs[g * STRIDE + ee], Wfc[ee], p);
            }
            p += __shfl_xor(p, 1);
            p += __shfl_xor(p, 2);
            if (q == 0) XWfcs[g] = p;                 // row 127 -> 0
        }
        __syncthreads();

        for (int t = 0; t < TM1; ++t) {
            // ==== R1: u[g] (full, via 4-lane shuffle) + z d-part into regs ====
            float c_old = sdc[128 + g];
            float pa = 0.0f;
            #pragma unroll
            for (int i4 = 0; i4 < 16; ++i4) {
                const float4 v = sdc4[q * 16 + ((i4 + q * 4) & 15)];
                const int ib = i4 * 4;
                pa = fmaf(w1r[ib + 0], v.x, pa); pa = fmaf(w1r[ib + 1], v.y, pa);
                pa = fmaf(w1r[ib + 2], v.z, pa); pa = fmaf(w1r[ib + 3], v.w, pa);
            }
            pa += __shfl_xor(pa, 1);
            pa += __shfl_xor(pa, 2);
            if (q == 0) u_s[g] = pa;

            float zp0 = 0.f, zp1 = 0.f, zp2 = 0.f, zp3 = 0.f;
            #pragma unroll
            for (int i4 = 0; i4 < 8; ++i4) {
                const float4 v = sdc4[q * 8 + ((i4 + q * 2) & 7)];
                const int ib = i4 * 4;
                zp0 = fmaf(whr[ib + 0], v.x, zp0); zp0 = fmaf(whr[ib + 1], v.y, zp0);
                zp0 = fmaf(whr[ib + 2], v.z, zp0); zp0 = fmaf(whr[ib + 3], v.w, zp0);
                zp1 = fmaf(whr[32 + ib + 0], v.x, zp1); zp1 = fmaf(whr[32 + ib + 1], v.y, zp1);
                zp1 = fmaf(whr[32 + ib + 2], v.z, zp1); zp1 = fmaf(whr[32 + ib + 3], v.w, zp1);
                zp2 = fmaf(whr[64 + ib + 0], v.x, zp2); zp2 = fmaf(whr[64 + ib + 1], v.y, zp2);
                zp2 = fmaf(whr[64 + ib + 2], v.z, zp2); zp2 = fmaf(whr[64 + ib + 3], v.w, zp2);
                zp3 = fmaf(whr[96 + ib + 0], v.x, zp3); zp3 = fmaf(whr[96 + ib + 1], v.y, zp3);
                zp3 = fmaf(whr[96 + ib + 2], v.z, zp3); zp3 = fmaf(whr[96 + ib + 3], v.w, zp3);
            }
            __syncthreads();                           // S1

            // ==== R2: beta[t'=g] + y_tilde partial (tanh-heavy) ====
            float p = b2q;
            #pragma unroll
            for (int i4 = 0; i4 < 8; ++i4) {
                const int j = q * 8 + ((i4 + q * 2) & 7);
                const float4 px = *(const float4*)&preX[g * STRIDE + j * 4];
                const float4 uu = u4p[j];
                const float4 ww = w24p[j];
                p = fmaf(fast_tanh(px.x + uu.x), ww.x, p);
                p = fmaf(fast_tanh(px.y + uu.y), ww.y, p);
                p = fmaf(fast_tanh(px.z + uu.z), ww.z, p);
                p = fmaf(fast_tanh(px.w + uu.w), ww.w, p);
            }
            p += __shfl_xor(p, 1);
            p += __shfl_xor(p, 2);                     // p = beta (all 4 lanes)
            if (t == TM1 - 1 && q == 0) betas[g] = p;  // needed for final ctx only
            float prod = p * XWfcs[g];                 // t'=127 -> *0
            prod += __shfl_xor(prod, 4);
            prod += __shfl_xor(prod, 8);
            prod += __shfl_xor(prod, 16);
            prod += __shfl_xor(prod, 32);              // sum over wave's 16 t'
            if ((tid & 63) == 0) swave[wv] = prod;
            __syncthreads();                           // S2

            // ==== R3: y_tilde (redundant), z, gates, state update ====
            {
                float s = swave[0] + swave[1] + swave[2] + swave[3]
                        + swave[4] + swave[5] + swave[6] + swave[7];
                float ytl = fmaf(ys[t], wfcy, s + bfc_r);
                zp0 += __shfl_xor(zp0, 1); zp0 += __shfl_xor(zp0, 2);
                zp1 += __shfl_xor(zp1, 1); zp1 += __shfl_xor(zp1, 2);
                zp2 += __shfl_xor(zp2, 1); zp2 += __shfl_xor(zp2, 2);
                zp3 += __shfl_xor(zp3, 1); zp3 += __shfl_xor(zp3, 2);
                float zi = fmaf(ytl, wx0, bl0) + zp0;
                float zf = fmaf(ytl, wx1, bl1) + zp1;
                float zg = fmaf(ytl, wx2, bl2) + zp2;
                float zo = fmaf(ytl, wx3, bl3) + zp3;
                float cn = fast_sig(zf) * c_old + fast_sig(zi) * fast_tanh(zg);
                float dn = fast_sig(zo) * fast_tanh(cn);
                if (q == 0) { sdc[g] = dn; sdc[128 + g] = cn; }
            }
            __syncthreads();                           // S3
        }

        // ---- epilogue: final ctx (once) + out = [d;ctx].Wf + bf ----
        if (tid < 128) {
            float cacc = 0.0f;
            for (int tp = 0; tp < TM1; ++tp)
                cacc = fmaf(betas[tp], Xs[tp * STRIDE + tid], cacc);
            scrE[tid] = fmaf(sdc[tid], Wf[tid], cacc * Wf[128 + tid]);
        }
        __syncthreads();
        if (tid < 64) {
            float pp = scrE[tid] + scrE[tid + 64];
            #pragma unroll
            for (int off = 32; off > 0; off >>= 1) pp += __shfl_down(pp, off);
            if (tid == 0) out[b] = pp + bf_r;
        }
        __syncthreads();                               // protect Xs/sdc before next round
    }
}

extern "C" void kernel_launch(void* const* d_in, const int* in_sizes, int n_in,
                              void* d_out, int out_size, void* d_ws, size_t ws_size,
                              hipStream_t stream) {
    (void)in_sizes; (void)n_in; (void)d_ws; (void)ws_size; (void)out_size;
    const float* Xg    = (const float*)d_in[0];
    const float* yprev = (const float*)d_in[1];
    const float* W1    = (const float*)d_in[2];
    const float* b1    = (const float*)d_in[3];
    const float* W2    = (const float*)d_in[4];
    const float* b2    = (const float*)d_in[5];
    const float* Wfc   = (const float*)d_in[6];
    const float* bfc   = (const float*)d_in[7];
    const float* Wx    = (const float*)d_in[8];
    const float* Wh    = (const float*)d_in[9];
    const float* bl    = (const float*)d_in[10];
    const float* Wf    = (const float*)d_in[11];
    const float* bf    = (const float*)d_in[12];
    decoder_kernel<<<NBLOCKS, NTHREADS, 0, stream>>>(
        Xg, yprev, W1, b1, W2, b2, Wfc, bfc, Wx, Wh, bl, Wf, bf, (float*)d_out);
}